// Round 1
// baseline (46.771 us; speedup 1.0000x reference)
//
#include <hip/hip_runtime.h>

// YOLO loss: pred/target (N,14,14,30) fp32 -> scalar.
// S=14, B=2, C=20, cell stride = 30 floats = 120 bytes.

#define S_DIM 14
#define CELLF 30
constexpr float LAMBDA_COORD = 5.0f;
constexpr float LAMBDA_NOOBJ = 0.5f;
constexpr float EPSF = 1e-7f;

__device__ __forceinline__ float iou_xywh(float cx1, float cy1, float w1, float h1,
                                          float cx2, float cy2, float w2, float h2) {
    float ix1 = fmaxf(cx1 - 0.5f * w1, cx2 - 0.5f * w2);
    float iy1 = fmaxf(cy1 - 0.5f * h1, cy2 - 0.5f * h2);
    float ix2 = fminf(cx1 + 0.5f * w1, cx2 + 0.5f * w2);
    float iy2 = fminf(cy1 + 0.5f * h1, cy2 + 0.5f * h2);
    float inter = fmaxf(ix2 - ix1, 0.0f) * fmaxf(iy2 - iy1, 0.0f);
    float uni = w1 * h1 + w2 * h2 - inter + EPSF;
    return inter / uni;
}

__global__ __launch_bounds__(256) void yolo_loss_kernel(
        const float* __restrict__ pred,
        const float* __restrict__ tgt,
        float* __restrict__ partial,
        int ncells) {
    int cell = blockIdx.x * blockDim.x + threadIdx.x;
    float loss = 0.0f;
    if (cell < ncells) {
        // 30 floats per cell = 15 float2 (cell byte offset 120*cell is 8B-aligned).
        const float2* pf = reinterpret_cast<const float2*>(pred) + (size_t)cell * 15;
        const float2* tf = reinterpret_cast<const float2*>(tgt) + (size_t)cell * 15;
        float p[CELLF], t[CELLF];
        #pragma unroll
        for (int k = 0; k < 15; ++k) {
            float2 a = pf[k];
            float2 b = tf[k];
            p[2 * k] = a.x; p[2 * k + 1] = a.y;
            t[2 * k] = b.x; t[2 * k + 1] = b.y;
        }
        // layout per cell: [0..4]=box0 cx,cy,w,h,conf  [5..9]=box1  [10..29]=classes
        float iou00 = iou_xywh(p[0], p[1], p[2], p[3], t[0], t[1], t[2], t[3]);
        float iou10 = iou_xywh(p[5], p[6], p[7], p[8], t[0], t[1], t[2], t[3]);
        float iou11 = iou_xywh(p[5], p[6], p[7], p[8], t[5], t[6], t[7], t[8]);

        bool obj = t[4] > 0.0f;          // tgt conf of box0 (== obj mask)
        bool best1 = iou10 > iou00;      // argmax first-max tie-break: box1 only if strictly greater

        float d0 = p[4] - t[4];  float c0 = d0 * d0;
        float d1 = p[9] - t[9];  float c1 = d1 * d1;
        float conf_best  = best1 ? c1 : c0;
        float conf_other = best1 ? c0 : c1;

        float iou_pair_best = best1 ? iou11 : iou00;
        float coord = 1.0f - sqrtf(fmaxf(iou_pair_best, EPSF));  // ALPHA=0.5

        float cls = 0.0f;
        #pragma unroll
        for (int k = 0; k < 20; ++k) {
            float d = p[10 + k] - t[10 + k];
            cls = fmaf(d, d, cls);
        }

        float loss_obj   = obj ? conf_best : 0.0f;
        float loss_noobj = obj ? conf_other : (c0 + c1);
        float loss_coord = obj ? coord : 0.0f;
        float loss_cls   = obj ? cls : 0.0f;

        loss = LAMBDA_COORD * loss_coord + loss_obj + LAMBDA_NOOBJ * loss_noobj + loss_cls;
    }

    // wave (64) shuffle reduce
    #pragma unroll
    for (int off = 32; off > 0; off >>= 1)
        loss += __shfl_down(loss, off, 64);

    __shared__ float wsum[4];
    int lane = threadIdx.x & 63;
    int wid  = threadIdx.x >> 6;
    if (lane == 0) wsum[wid] = loss;
    __syncthreads();
    if (threadIdx.x == 0)
        partial[blockIdx.x] = wsum[0] + wsum[1] + wsum[2] + wsum[3];
}

__global__ __launch_bounds__(256) void yolo_reduce_kernel(
        const float* __restrict__ partial, int n,
        float* __restrict__ out, float inv_n) {
    double s = 0.0;
    for (int i = threadIdx.x; i < n; i += 256)
        s += (double)partial[i];
    #pragma unroll
    for (int off = 32; off > 0; off >>= 1)
        s += __shfl_down(s, off, 64);
    __shared__ double wsum[4];
    int lane = threadIdx.x & 63;
    int wid  = threadIdx.x >> 6;
    if (lane == 0) wsum[wid] = s;
    __syncthreads();
    if (threadIdx.x == 0) {
        double tot = wsum[0] + wsum[1] + wsum[2] + wsum[3];
        out[0] = (float)(tot * (double)inv_n);
    }
}

extern "C" void kernel_launch(void* const* d_in, const int* in_sizes, int n_in,
                              void* d_out, int out_size, void* d_ws, size_t ws_size,
                              hipStream_t stream) {
    const float* pred = (const float*)d_in[0];
    const float* tgt  = (const float*)d_in[1];
    float* out = (float*)d_out;

    int total_elems = in_sizes[0];          // N * S * S * 30
    int ncells = total_elems / CELLF;       // N * 196
    int N = ncells / (S_DIM * S_DIM);       // 4096

    int blocks = (ncells + 255) / 256;      // 3136
    float* partial = (float*)d_ws;          // blocks * 4 bytes needed (~12.5 KB)

    yolo_loss_kernel<<<blocks, 256, 0, stream>>>(pred, tgt, partial, ncells);
    yolo_reduce_kernel<<<1, 256, 0, stream>>>(partial, blocks, out, 1.0f / (float)N);
}

// Round 2
// 38.048 us; speedup vs baseline: 1.2293x; 1.2293x over previous
//
#include <hip/hip_runtime.h>

// YOLO loss: pred/target (N,14,14,30) fp32 -> scalar.
// S=14, B=2, C=20, cell stride = 30 floats = 120 bytes.
//
// R1: coalesced LDS staging. Each 256-thread block stages 256 cells
// (7680 floats per array) via float4 loads (15 per thread across both
// arrays), then each thread computes its cell from LDS.

#define S_DIM 14
#define CELLF 30
#define TPB 256
#define CHUNKF (TPB * CELLF)   // 7680 floats per array per block
#define CHUNK4 (CHUNKF / 4)    // 1920 float4 per array per block

constexpr float LAMBDA_COORD = 5.0f;
constexpr float LAMBDA_NOOBJ = 0.5f;
constexpr float EPSF = 1e-7f;

__device__ __forceinline__ float iou_xywh(float cx1, float cy1, float w1, float h1,
                                          float cx2, float cy2, float w2, float h2) {
    float ix1 = fmaxf(cx1 - 0.5f * w1, cx2 - 0.5f * w2);
    float iy1 = fmaxf(cy1 - 0.5f * h1, cy2 - 0.5f * h2);
    float ix2 = fminf(cx1 + 0.5f * w1, cx2 + 0.5f * w2);
    float iy2 = fminf(cy1 + 0.5f * h1, cy2 + 0.5f * h2);
    float inter = fmaxf(ix2 - ix1, 0.0f) * fmaxf(iy2 - iy1, 0.0f);
    float uni = w1 * h1 + w2 * h2 - inter + EPSF;
    return inter / uni;
}

__global__ __launch_bounds__(TPB) void yolo_loss_kernel(
        const float* __restrict__ pred,
        const float* __restrict__ tgt,
        float* __restrict__ partial,
        int ncells) {
    // LDS: [0 .. CHUNKF) = pred cells, [CHUNKF .. 2*CHUNKF) = tgt cells (linear)
    __shared__ float lds[2 * CHUNKF];   // 61440 B -> 2 blocks/CU

    const int tid = threadIdx.x;
    const size_t base4 = (size_t)blockIdx.x * CHUNK4;   // float4 idx into each array
    const size_t n4 = (size_t)ncells * CELLF / 4;       // total float4 per array
    const float4* pred4 = reinterpret_cast<const float4*>(pred);
    const float4* tgt4  = reinterpret_cast<const float4*>(tgt);

    // ---- stage: 15 coalesced float4 loads per thread (pred then tgt regions)
    float4 stage[15];
    #pragma unroll
    for (int k = 0; k < 15; ++k) {
        int i = tid + k * TPB;                 // 0..3839 across block
        size_t gi;
        const float4* src;
        if (i < CHUNK4) { src = pred4; gi = base4 + i; }
        else            { src = tgt4;  gi = base4 + (i - CHUNK4); }
        if (gi >= n4) gi = n4 - 1;             // clamp (no-op for exact grids)
        stage[k] = src[gi];
    }
    #pragma unroll
    for (int k = 0; k < 15; ++k) {
        int i = tid + k * TPB;
        reinterpret_cast<float4*>(lds)[i] = stage[k];   // contiguous, conflict-free
    }
    __syncthreads();

    // ---- compute: one cell per thread from LDS
    int cell = blockIdx.x * TPB + tid;
    float loss = 0.0f;
    if (cell < ncells) {
        const float* lp = &lds[tid * CELLF];
        const float* lt = &lds[CHUNKF + tid * CELLF];
        float p[CELLF], t[CELLF];
        #pragma unroll
        for (int k = 0; k < CELLF; ++k) { p[k] = lp[k]; t[k] = lt[k]; }

        // layout per cell: [0..4]=box0 cx,cy,w,h,conf  [5..9]=box1  [10..29]=classes
        float iou00 = iou_xywh(p[0], p[1], p[2], p[3], t[0], t[1], t[2], t[3]);
        float iou10 = iou_xywh(p[5], p[6], p[7], p[8], t[0], t[1], t[2], t[3]);
        float iou11 = iou_xywh(p[5], p[6], p[7], p[8], t[5], t[6], t[7], t[8]);

        bool obj = t[4] > 0.0f;          // tgt conf of box0 (== obj mask)
        bool best1 = iou10 > iou00;      // argmax first-max tie-break

        float d0 = p[4] - t[4];  float c0 = d0 * d0;
        float d1 = p[9] - t[9];  float c1 = d1 * d1;
        float conf_best  = best1 ? c1 : c0;
        float conf_other = best1 ? c0 : c1;

        float iou_pair_best = best1 ? iou11 : iou00;
        float coord = 1.0f - sqrtf(fmaxf(iou_pair_best, EPSF));  // ALPHA=0.5

        float cls = 0.0f;
        #pragma unroll
        for (int k = 0; k < 20; ++k) {
            float d = p[10 + k] - t[10 + k];
            cls = fmaf(d, d, cls);
        }

        float loss_obj   = obj ? conf_best : 0.0f;
        float loss_noobj = obj ? conf_other : (c0 + c1);
        float loss_coord = obj ? coord : 0.0f;
        float loss_cls   = obj ? cls : 0.0f;

        loss = LAMBDA_COORD * loss_coord + loss_obj + LAMBDA_NOOBJ * loss_noobj + loss_cls;
    }

    // ---- block reduce
    #pragma unroll
    for (int off = 32; off > 0; off >>= 1)
        loss += __shfl_down(loss, off, 64);

    __shared__ float wsum[4];
    int lane = tid & 63;
    int wid  = tid >> 6;
    if (lane == 0) wsum[wid] = loss;
    __syncthreads();
    if (tid == 0)
        partial[blockIdx.x] = wsum[0] + wsum[1] + wsum[2] + wsum[3];
}

__global__ __launch_bounds__(256) void yolo_reduce_kernel(
        const float* __restrict__ partial, int n,
        float* __restrict__ out, float inv_n) {
    double s = 0.0;
    for (int i = threadIdx.x; i < n; i += 256)
        s += (double)partial[i];
    #pragma unroll
    for (int off = 32; off > 0; off >>= 1)
        s += __shfl_down(s, off, 64);
    __shared__ double wsum[4];
    int lane = threadIdx.x & 63;
    int wid  = threadIdx.x >> 6;
    if (lane == 0) wsum[wid] = s;
    __syncthreads();
    if (threadIdx.x == 0) {
        double tot = wsum[0] + wsum[1] + wsum[2] + wsum[3];
        out[0] = (float)(tot * (double)inv_n);
    }
}

extern "C" void kernel_launch(void* const* d_in, const int* in_sizes, int n_in,
                              void* d_out, int out_size, void* d_ws, size_t ws_size,
                              hipStream_t stream) {
    const float* pred = (const float*)d_in[0];
    const float* tgt  = (const float*)d_in[1];
    float* out = (float*)d_out;

    int total_elems = in_sizes[0];          // N * S * S * 30
    int ncells = total_elems / CELLF;       // N * 196
    int N = ncells / (S_DIM * S_DIM);       // 4096

    int blocks = (ncells + TPB - 1) / TPB;  // 3136
    float* partial = (float*)d_ws;          // blocks * 4 B (~12.5 KB)

    yolo_loss_kernel<<<blocks, TPB, 0, stream>>>(pred, tgt, partial, ncells);
    yolo_reduce_kernel<<<1, 256, 0, stream>>>(partial, blocks, out, 1.0f / (float)N);
}